// Round 1
// 1297.100 us; speedup vs baseline: 1.0923x; 1.0923x over previous
//
#include <hip/hip_runtime.h>
#include <cstdint>

using u16 = unsigned short;
using u32 = unsigned int;

typedef __bf16 bf16x8 __attribute__((ext_vector_type(8)));
typedef float  floatx4 __attribute__((ext_vector_type(4)));

#define DEV static __device__ __forceinline__

// ---------- helpers ----------
DEV u16 f2bf(float f) {                 // f32 -> bf16 RNE
    u32 u = __float_as_uint(f);
    u += 0x7FFFu + ((u >> 16) & 1u);
    return (u16)(u >> 16);
}
DEV float bf2f(u16 v) { return __uint_as_float(((u32)v) << 16); }

DEV floatx4 mfma32(bf16x8 a, bf16x8 b, floatx4 c) {
    return __builtin_amdgcn_mfma_f32_16x16x32_bf16(a, b, c, 0, 0, 0);
}

DEV floatx4 fzero() { floatx4 z; z[0]=0.f; z[1]=0.f; z[2]=0.f; z[3]=0.f; return z; }

typedef __attribute__((address_space(3))) u32 as3_u32;
typedef __attribute__((address_space(1))) u32 as1_u32;

// async global->LDS, 16B per lane; LDS dest = wave-uniform base + lane*16.
DEV void async_ld16(const u16* g, u16* l) {
    __builtin_amdgcn_global_load_lds(
        (const as1_u32*)g, (as3_u32*)l, 16, 0, 0);
}

// ---------- weight transpose: W[K][N] f32 -> Wt[N][K] bf16 ----------
__global__ __launch_bounds__(256) void transpose_w(
    const float* __restrict__ W, u16* __restrict__ Wt, int K, int N)
{
    __shared__ float t[32][33];
    const int tx = threadIdx.x, ty = threadIdx.y;   // block 32x8
    const int gx = blockIdx.x * 32;                 // N dim
    const int gy = blockIdx.y * 32;                 // K dim
    #pragma unroll
    for (int i = 0; i < 4; ++i)
        t[ty + i*8][tx] = W[(size_t)(gy + ty + i*8) * N + gx + tx];
    __syncthreads();
    #pragma unroll
    for (int i = 0; i < 4; ++i)
        Wt[(size_t)(gx + ty + i*8) * K + gy + tx] = f2bf(t[tx][ty + i*8]);
}

// ---------- LayerNorm (wave per row, 4 rows/block), writes bf16 ----------
template<int MODE>
__global__ __launch_bounds__(256) void ln_kernel(
    const float* __restrict__ xp, const u16* __restrict__ xt2,
    const float* __restrict__ w, const float* __restrict__ b,
    u16* __restrict__ out, int nrows)
{
    const int row = blockIdx.x * 4 + (threadIdx.x >> 6);
    if (row >= nrows) return;
    const int lane = threadIdx.x & 63;
    float vals[12];
    if constexpr (MODE == 0) {
        const float* src = xp + (size_t)(row + row/3136 + 1) * 768;
        #pragma unroll
        for (int j = 0; j < 3; ++j) {
            float4 v = reinterpret_cast<const float4*>(src)[j*64 + lane];
            vals[j*4+0]=v.x; vals[j*4+1]=v.y; vals[j*4+2]=v.z; vals[j*4+3]=v.w;
        }
    } else {
        const int bt = row / 197;
        const int p  = row - bt * 197;
        const int b0 = bt >> 4, tt = bt & 15;
        if (p == 0) {
            const float* src = xp + (size_t)b0 * 3137 * 768;
            #pragma unroll
            for (int j = 0; j < 3; ++j) {
                float4 v = reinterpret_cast<const float4*>(src)[j*64 + lane];
                vals[j*4+0]=v.x; vals[j*4+1]=v.y; vals[j*4+2]=v.z; vals[j*4+3]=v.w;
            }
        } else {
            const u16* src = xt2 + (size_t)(b0*3136 + (p-1)*16 + tt) * 768;
            #pragma unroll
            for (int j = 0; j < 3; ++j) {
                uint2 q = reinterpret_cast<const uint2*>(src)[j*64 + lane];
                vals[j*4+0] = bf2f((u16)(q.x & 0xFFFF));
                vals[j*4+1] = bf2f((u16)(q.x >> 16));
                vals[j*4+2] = bf2f((u16)(q.y & 0xFFFF));
                vals[j*4+3] = bf2f((u16)(q.y >> 16));
            }
        }
    }
    float s = 0.f, ss = 0.f;
    #pragma unroll
    for (int e = 0; e < 12; ++e) { s += vals[e]; ss += vals[e]*vals[e]; }
    #pragma unroll
    for (int o = 32; o > 0; o >>= 1) { s += __shfl_xor(s, o); ss += __shfl_xor(ss, o); }
    const float mean = s * (1.f/768.f);
    const float var  = ss * (1.f/768.f) - mean*mean;
    const float rstd = rsqrtf(var + 1e-5f);
    #pragma unroll
    for (int j = 0; j < 3; ++j) {
        const int c4 = (j*64 + lane) * 4;
        union { u16 u[4]; uint2 q; } o;
        #pragma unroll
        for (int e = 0; e < 4; ++e)
            o.u[e] = f2bf((vals[j*4+e] - mean)*rstd*w[c4+e] + b[c4+e]);
        *reinterpret_cast<uint2*>(&out[(size_t)row*768 + c4]) = o.q;
    }
}

// ---------- combine: x_new = concat residuals (f32 -> d_out), then LN(n2) bf16 ----------
__global__ __launch_bounds__(256) void combine_ln2(
    const float* __restrict__ xp, const u16* __restrict__ xt2,
    const u16* __restrict__ rsb, const float* __restrict__ w, const float* __restrict__ b,
    float* __restrict__ xnew, u16* __restrict__ ln2, int nrows)
{
    const int row = blockIdx.x * 4 + (threadIdx.x >> 6);
    if (row >= nrows) return;
    const int lane = threadIdx.x & 63;
    const int b0 = row / 3137;
    const int j  = row - b0 * 3137;
    float vals[12];
    if (j == 0) {       // cls row: x[b,0] + mean_t rs[(b,t) seq, token 0]
        #pragma unroll
        for (int e = 0; e < 12; ++e) {
            const int c = e*64 + lane;
            float acc = 0.f;
            for (int t = 0; t < 16; ++t)
                acc += bf2f(rsb[(size_t)(b0*16 + t) * 197 * 768 + c]);
            vals[e] = xp[(size_t)row*768 + c] + acc * (1.f/16.f);
        }
    } else {
        const int n_idx = j - 1;
        const int hw = n_idx >> 4, tt = n_idx & 15;
        const u16* a  = xt2 + (size_t)(b0*3136 + n_idx) * 768;
        const u16* r2 = rsb + (size_t)((b0*16 + tt)*197 + 1 + hw) * 768;
        #pragma unroll
        for (int e = 0; e < 12; ++e) {
            const int c = e*64 + lane;
            vals[e] = bf2f(a[c]) + bf2f(r2[c]);
        }
    }
    float s = 0.f, ss = 0.f;
    #pragma unroll
    for (int e = 0; e < 12; ++e) { s += vals[e]; ss += vals[e]*vals[e]; }
    #pragma unroll
    for (int o = 32; o > 0; o >>= 1) { s += __shfl_xor(s, o); ss += __shfl_xor(ss, o); }
    const float mean = s * (1.f/768.f);
    const float var  = ss * (1.f/768.f) - mean*mean;
    const float rstd = rsqrtf(var + 1e-5f);
    #pragma unroll
    for (int e = 0; e < 12; ++e) {
        const int c = e*64 + lane;
        xnew[(size_t)row*768 + c] = vals[e];
        ln2[(size_t)row*768 + c]  = f2bf((vals[e] - mean)*rstd*w[c] + b[c]);
    }
}

// ============================================================================
// GEMM 256x256 tile, BK=64, 8 waves (2Mx4N), 8-phase schedule (T2+T3+T4+T5).
//   - LDS 128 KiB: 2 dbuf x {A[2 halves of 128r x 64k], B[same]} bf16.
//   - XOR chunk swizzle: physical 16B-chunk p of row r holds logical chunk
//     p ^ (r&7); achieved by pre-swizzling the GLOBAL source (gload_lds dest
//     must stay lane-linear). ds_read_b128 -> 2-way bank spread (free).
//   - staging: 1 half-tile (2 x global_load_lds dwordx4 per wave) per phase;
//     per-K-tile order B.h0,B.h1,A.h0,A.h1 timed so a region is only
//     overwritten >=1 barrier after its last read (liveness: B dead after
//     phase2 of its tile, A dead after phase3).
//   - vmcnt(4) gates only at phases 4 and 8: exactly 4 loads (2 half-tiles)
//     trail the tile being gated. Never vmcnt(0) in steady state.
//   - setprio(1) around each 16-MFMA cluster.
// ============================================================================

#define BARX() do { __builtin_amdgcn_sched_barrier(0); asm volatile("" ::: "memory"); \
    __builtin_amdgcn_s_barrier(); asm volatile("" ::: "memory"); \
    __builtin_amdgcn_sched_barrier(0); } while(0)
#define WAITL() do { asm volatile("s_waitcnt lgkmcnt(0)" ::: "memory"); \
    __builtin_amdgcn_sched_barrier(0); } while(0)
#define WAITV4() do { asm volatile("s_waitcnt vmcnt(4)" ::: "memory"); \
    __builtin_amdgcn_sched_barrier(0); } while(0)
#define WAITV0() do { asm volatile("s_waitcnt vmcnt(0)" ::: "memory"); \
    __builtin_amdgcn_sched_barrier(0); } while(0)

// read 4 A-frags (m-half mh of this wave's 128 rows) x 2 ksteps from buf d
#define RD_A(d, mh) do { \
    _Pragma("unroll") for (int ff = 0; ff < 4; ++ff) { \
      _Pragma("unroll") for (int ks = 0; ks < 2; ++ks) { \
        const int rr = ((mh)*4 + ff)*16 + m15; \
        a[ff*2+ks] = *reinterpret_cast<const bf16x8*>( \
            &sm[(d)*32768 + wm*8192 + rr*64 + ((ks*4 + quad) ^ (m15 & 7))*8]); \
    } } } while(0)

// read 2 B-frags (n-pair np: frags np*2, np*2+1) x 2 ksteps from buf d
#define RD_B(d, np) do { \
    _Pragma("unroll") for (int nn = 0; nn < 2; ++nn) { \
      _Pragma("unroll") for (int ks = 0; ks < 2; ++ks) { \
        const int rr = (wn & 1)*64 + ((np)*2 + nn)*16 + m15; \
        b[((np)*2 + nn)*2 + ks] = *reinterpret_cast<const bf16x8*>( \
            &sm[(d)*32768 + 16384 + (wn >> 1)*8192 + rr*64 + ((ks*4 + quad) ^ (m15 & 7))*8]); \
    } } } while(0)

// 16 MFMAs: acc rows F0..F0+3, cols NF0..NF0+1, both ksteps
#define MQ(F0, NF0) do { \
    _Pragma("unroll") for (int ff = 0; ff < 4; ++ff) { \
      _Pragma("unroll") for (int nn = 0; nn < 2; ++nn) { \
        floatx4 c_ = acc[(F0)+ff][(NF0)+nn]; \
        c_ = mfma32(a[ff*2+0], b[((NF0)+nn)*2+0], c_); \
        c_ = mfma32(a[ff*2+1], b[((NF0)+nn)*2+1], c_); \
        acc[(F0)+ff][(NF0)+nn] = c_; \
    } } } while(0)

#define PRIO1() __builtin_amdgcn_s_setprio(1)
#define PRIO0() __builtin_amdgcn_s_setprio(0)

// one iteration = K-tiles (tt, tt+1). FULL=1: steady staging; FULL=0: drain.
#define ITER(tt, FULL) do { \
    const int d_ = (tt) & 1; \
    /* p1 */ RD_A(d_, 0); RD_B(d_, 0); STAGE((tt)+1, 2); \
    BARX(); WAITL(); PRIO1(); MQ(0,0); PRIO0(); BARX(); \
    /* p2 */ RD_B(d_, 1); STAGE((tt)+1, 3); \
    BARX(); WAITL(); PRIO1(); MQ(0,2); PRIO0(); BARX(); \
    /* p3 */ RD_A(d_, 1); if (FULL) STAGE((tt)+2, 0); \
    BARX(); WAITL(); PRIO1(); MQ(4,2); PRIO0(); BARX(); \
    /* p4 */ if (FULL) STAGE((tt)+2, 1); \
    BARX(); PRIO1(); MQ(4,0); PRIO0(); \
    if (FULL) WAITV4(); else WAITV0(); \
    BARX(); \
    /* p5 */ RD_A(d_^1, 0); RD_B(d_^1, 0); if (FULL) STAGE((tt)+2, 2); \
    BARX(); WAITL(); PRIO1(); MQ(0,0); PRIO0(); BARX(); \
    /* p6 */ RD_B(d_^1, 1); if (FULL) STAGE((tt)+2, 3); \
    BARX(); WAITL(); PRIO1(); MQ(0,2); PRIO0(); BARX(); \
    /* p7 */ RD_A(d_^1, 1); if (FULL) STAGE((tt)+3, 0); \
    BARX(); WAITL(); PRIO1(); MQ(4,2); PRIO0(); BARX(); \
    /* p8 */ if (FULL) STAGE((tt)+3, 1); \
    BARX(); PRIO1(); MQ(4,0); PRIO0(); \
    if (FULL) WAITV4(); \
    BARX(); \
} while(0)

// RESID: 0 none, 1 f32 resid[row*N+col], 2 f32 x-skip-cls resid[(row+row/3136+1)*768+col]
template<int RESID, bool BIAS, bool GELU_ACT, bool OUTF, bool OUTB, bool MASKM>
__global__ __launch_bounds__(512, 2) void gemm256(
    const u16* __restrict__ A, const u16* __restrict__ Bt,
    const float* __restrict__ bias, const float* __restrict__ resid,
    float* __restrict__ Cf, u16* __restrict__ Cb,
    int N, int K, int lda, int ldb, int Mvalid)
{
    extern __shared__ u16 sm[];
    const int tid  = threadIdx.x;
    const int w    = tid >> 6;
    const int l    = tid & 63;
    const int m15  = l & 15;
    const int quad = l >> 4;
    const int wm   = w >> 2;     // 0..1  (M half: 128 rows)
    const int wn   = w & 3;      // 0..3  (N quarter: 64 cols)
    const long m0  = (long)blockIdx.y * 256;
    const long n0  = (long)blockIdx.x * 256;

    // staging geometry: lane covers row (w*8 + l/8) (+64 per 2nd issue,
    // +128 per half), logical 16B-chunk (l&7)^(l>>3)  [inverse swizzle]
    const int srow   = w*8 + (l >> 3);
    const int schunk = ((l & 7) ^ (l >> 3)) * 8;
    const u16* gA = A  + (size_t)(m0 + srow) * lda + schunk;
    const u16* gB = Bt + (size_t)(n0 + srow) * ldb + schunk;
    const int w512 = w * 512;

    auto STAGE = [&](int tt, int h4) {   // h4: 0=B.h0 1=B.h1 2=A.h0 3=A.h1
        const int dd = tt & 1;
        const int k0 = tt << 6;
        const int h  = h4 & 1;
        if (h4 & 2) {
            const u16* g = gA + (size_t)(h * 128) * lda + k0;
            u16* lp = sm + dd*32768 + h*8192 + w512;
            async_ld16(g, lp);
            async_ld16(g + (size_t)(64 * lda), lp + 4096);
        } else {
            const u16* g = gB + (size_t)(h * 128) * ldb + k0;
            u16* lp = sm + dd*32768 + 16384 + h*8192 + w512;
            async_ld16(g, lp);
            async_ld16(g + (size_t)(64 * ldb), lp + 4096);
        }
    };

    bf16x8 a[8], b[8];
    floatx4 acc[8][4];
    #pragma unroll
    for (int f = 0; f < 8; ++f)
        #pragma unroll
        for (int nf = 0; nf < 4; ++nf) acc[f][nf] = fzero();

    const int NIT = K >> 7;    // K/128, >= 2 for all our shapes

    // prologue: tile0 fully + tile1 B halves (12 loads); gate tile0 (4 trail)
    STAGE(0, 0); STAGE(0, 1); STAGE(0, 2); STAGE(0, 3);
    STAGE(1, 0); STAGE(1, 1);
    WAITV4(); BARX();

    int t = 0;
    for (int i = 0; i < NIT - 1; ++i, t += 2) { ITER(t, 1); }
    ITER(t, 0);

    // ---------------- epilogue ----------------
    float bv[4];
    #pragma unroll
    for (int nf = 0; nf < 4; ++nf)
        bv[nf] = BIAS ? bias[n0 + wn*64 + nf*16 + m15] : 0.f;

    if constexpr (OUTB) {
        // vmcnt==0 here (drained at final p4, no stages after): LDS is free.
        // Each wave stages its own 128x64 bf16 C tile (16 KB) in its slot,
        // then stores 16B-aligned uint4 lines. Wave-local -> no barrier.
        u16* cst = sm + w * 8192;
        #pragma unroll
        for (int f = 0; f < 8; ++f) {
            #pragma unroll
            for (int nf = 0; nf < 4; ++nf) {
                #pragma unroll
                for (int r = 0; r < 4; ++r) {
                    const long row = m0 + wm*128 + f*16 + quad*4 + r;
                    float v = acc[f][nf][r] + bv[nf];
                    if constexpr (RESID == 1)
                        v += resid[(size_t)row * N + (n0 + wn*64 + nf*16 + m15)];
                    if constexpr (RESID == 2)
                        v += resid[(size_t)(row + row/3136 + 1) * 768 + (n0 + wn*64 + nf*16 + m15)];
                    if constexpr (GELU_ACT)
                        v = 0.5f * v * (1.f + erff(v * 0.70710678118f));
                    cst[(f*16 + quad*4 + r)*64 + nf*16 + m15] = f2bf(v);
                }
            }
        }
        #pragma unroll
        for (int it = 0; it < 16; ++it) {
            const int lr = it*8 + (l >> 3);
            const long grow = m0 + wm*128 + lr;
            if constexpr (MASKM) { if (grow >= Mvalid) continue; }
            const int cc = (l & 7) * 8;
            *reinterpret_cast<uint4*>(&Cb[(size_t)grow * N + n0 + wn*64 + cc]) =
                *reinterpret_cast<const uint4*>(&cst[lr*64 + cc]);
        }
    } else {
        #pragma unroll
        for (int f = 0; f < 8; ++f) {
            #pragma unroll
            for (int nf = 0; nf < 4; ++nf) {
                const long col = n0 + wn*64 + nf*16 + m15;
                #pragma unroll
                for (int r = 0; r < 4; ++r) {
                    const long row = m0 + wm*128 + f*16 + quad*4 + r;
                    if constexpr (MASKM) { if (row >= Mvalid) continue; }
                    float v = acc[f][nf][r] + bv[nf];
                    if constexpr (RESID == 1) v += resid[(size_t)row * N + col];
                    if constexpr (RESID == 2) v += resid[(size_t)(row + row/3136 + 1) * 768 + col];
                    if constexpr (GELU_ACT)   v = 0.5f * v * (1.f + erff(v * 0.70710678118f));
                    if constexpr (OUTF) Cf[(size_t)row * N + col] = v;
                }
            }
        }
    }
}

// ---------- fused attention (flash-style), one wave per (seq, head, q-tile) ----------
template<int S, int NQ, int NIT>
__global__ __launch_bounds__(256) void attn_kernel(
    const u16* __restrict__ qkv, u16* __restrict__ out, int ntask)
{
    __shared__ __attribute__((aligned(16))) u16 P_lds[4][16*32];
    const int wave = threadIdx.x >> 6;
    const int lane = threadIdx.x & 63;
    const int task = blockIdx.x * 4 + wave;
    if (task >= ntask) return;
    const int seq  = task / (12 * NQ);
    const int rem  = task - seq * (12 * NQ);
    const int head = rem / NQ;
    const int qt   = rem - head * NQ;
    const int m15  = lane & 15;
    const int quad = lane >> 4;
    const size_t base = (size_t)seq * S;

    const u16* qp = qkv + (base + qt*16 + m15) * 2304 + head*64 + quad*8;
    const bf16x8 Qf0 = *reinterpret_cast<const bf16x8*>(qp);
    const bf16x8 Qf1 = *reinterpret_cast<const bf16x8*>(qp + 32);

    floatx4 Oacc[4];
    #pragma unroll
    for (int c = 0; c < 4; ++c) Oacc[c] = fzero();
    float mrun = -__builtin_inff();
    float lrun = 0.f;
    u16* P = &P_lds[wave][0];

    for (int it = 0; it < NIT; ++it) {
        const int j0 = it * 32;
        floatx4 st[2];
        #pragma unroll
        for (int h2 = 0; h2 < 2; ++h2) {
            const u16* kp = qkv + (base + j0 + h2*16 + m15) * 2304 + 768 + head*64 + quad*8;
            const bf16x8 K0 = *reinterpret_cast<const bf16x8*>(kp);
            const bf16x8 K1 = *reinterpret_cast<const bf16x8*>(kp + 32);
            floatx4 z = fzero();
            z = mfma32(K0, Qf0, z);
            st[h2] = mfma32(K1, Qf1, z);
        }
        float sc[8];
        #pragma unroll
        for (int h2 = 0; h2 < 2; ++h2)
            #pragma unroll
            for (int r = 0; r < 4; ++r) {
                const int jj = j0 + h2*16 + quad*4 + r;
                sc[h2*4+r] = (jj < S) ? st[h2][r] * 0.125f : -__builtin_inff();
            }
        float tmax = sc[0];
        #pragma unroll
        for (int k = 1; k < 8; ++k) tmax = fmaxf(tmax, sc[k]);
        tmax = fmaxf(tmax, __shfl_xor(tmax, 16));
        tmax = fmaxf(tmax, __shfl_xor(tmax, 32));
        const float mnew = fmaxf(mrun, tmax);
        float p[8], tsum = 0.f;
        #pragma unroll
        for (int k = 0; k < 8; ++k) { p[k] = __expf(sc[k] - mnew); tsum += p[k]; }
        tsum += __shfl_xor(tsum, 16);
        tsum += __shfl_xor(tsum, 32);
        const float alpha = __expf(mrun - mnew);
        lrun = lrun * alpha + tsum;
        mrun = mnew;
        #pragma unroll
        for (int r = 0; r < 4; ++r) {             // rescale O rows (row = quad*4+r)
            const float ar = __shfl(alpha, quad*4 + r);
            #pragma unroll
            for (int c = 0; c < 4; ++c) Oacc[c][r] *= ar;
        }
        // P round-trip through LDS: C-layout -> A-operand layout
        #pragma unroll
        for (int h2 = 0; h2 < 2; ++h2)
            #pragma unroll
            for (int r = 0; r < 4; ++r)
                P[m15*32 + h2*16 + quad*4 + r] = f2bf(p[h2*4+r]);
        const bf16x8 Pf = *reinterpret_cast<const bf16x8*>(&P[m15*32 + quad*8]);
        #pragma unroll
        for (int c = 0; c < 4; ++c) {             // V in B-operand layout (scattered u16)
            union { u16 u[8]; bf16x8 v; } vf;
            #pragma unroll
            for (int jj2 = 0; jj2 < 8; ++jj2)
                vf.u[jj2] = qkv[(base + j0 + quad*8 + jj2) * 2304 + 1536 + head*64 + c*16 + m15];
            Oacc[c] = mfma32(Pf, vf.v, Oacc[c]);
        }
    }
    const float linv_self = 1.f / lrun;
    #pragma unroll
    for (int r = 0; r < 4; ++r) {
        const int prow = qt*16 + quad*4 + r;
        const float linv = __shfl(linv_self, quad*4 + r);
        if (prow < S) {
            u16* op = out + (base + prow) * 768 + head*64 + m15;
            #pragma unroll
            for (int c = 0; c < 4; ++c) op[c*16] = f2bf(Oacc[c][r] * linv);
        }
    }
}

// ---------- host ----------
extern "C" void kernel_launch(void* const* d_in, const int* in_sizes, int n_in,
                              void* d_out, int out_size, void* d_ws, size_t ws_size,
                              hipStream_t stream)
{
    (void)in_sizes; (void)n_in; (void)out_size; (void)ws_size;
    const float* x        = (const float*)d_in[0];
    const float* tn1_w    = (const float*)d_in[1];
    const float* tn1_b    = (const float*)d_in[2];
    const float* t_qkv_w  = (const float*)d_in[3];
    const float* t_proj_w = (const float*)d_in[4];
    const float* t_proj_b = (const float*)d_in[5];
    const float* tfc_w    = (const float*)d_in[6];
    const float* tfc_b    = (const float*)d_in[7];
    const float* n1_w     = (const float*)d_in[8];
    const float* n1_b     = (const float*)d_in[9];
    const float* s_qkv_w  = (const float*)d_in[10];
    const float* s_proj_w = (const float*)d_in[11];
    const float* s_proj_b = (const float*)d_in[12];
    const float* n2_w     = (const float*)d_in[13];
    const float* n2_b     = (const float*)d_in[14];
    const float* fc1_w    = (const float*)d_in[15];
    const float* fc1_b    = (const float*)d_in[16];
    const float* fc2_w    = (const float*)d_in[17];
    const float* fc2_b    = (const float*)d_in[18];
    float* out = (float*)d_out;

    char* ws = (char*)d_ws;
    size_t off = 0;
    auto alloc = [&](size_t bytes) -> void* {
        void* p = ws + off;
        off += (bytes + 255) & ~(size_t)255;
        return p;
    };
    // weights (bf16, transposed to [N][K])           total ~20.1 MB
    u16* wt_tqkv  = (u16*)alloc((size_t)768*2304*2);
    u16* wt_tproj = (u16*)alloc((size_t)768*768*2);
    u16* wt_tfc   = (u16*)alloc((size_t)768*768*2);
    u16* wt_sqkv  = (u16*)alloc((size_t)768*2304*2);
    u16* wt_sproj = (u16*)alloc((size_t)768*768*2);
    u16* wt_fc1   = (u16*)alloc((size_t)768*3072*2);
    u16* wt_fc2   = (u16*)alloc((size_t)3072*768*2);
    // activation slots (aliased lifetimes). Slots read as GEMM-A with a
    // 99th 256-row M-tile need 25344 rows allocated (tail rows = garbage,
    // masked on store).
    u16* slotA = (u16*)alloc((size_t)25280*2304*2);  // qkv_t / qkv_s / h1 (116.5 MB)
    u16* slotB = (u16*)alloc((size_t)25216*768*2);   // xt2 bf16 (38.7 MB)
    u16* slotD = (u16*)alloc((size_t)25344*768*2);   // ln_t/attn_t/ln_s/attn_s/ln2 (38.9 MB)
    u16* slotE = (u16*)alloc((size_t)25216*768*2);   // hp / rs bf16 (38.7 MB)

    dim3 tb(32, 8);
    transpose_w<<<dim3(72, 24), tb, 0, stream>>>(t_qkv_w,  wt_tqkv,  768, 2304);
    transpose_w<<<dim3(24, 24), tb, 0, stream>>>(t_proj_w, wt_tproj, 768, 768);
    transpose_w<<<dim3(24, 24), tb, 0, stream>>>(tfc_w,    wt_tfc,   768, 768);
    transpose_w<<<dim3(72, 24), tb, 0, stream>>>(s_qkv_w,  wt_sqkv,  768, 2304);
    transpose_w<<<dim3(24, 24), tb, 0, stream>>>(s_proj_w, wt_sproj, 768, 768);
    transpose_w<<<dim3(96, 24), tb, 0, stream>>>(fc1_w,    wt_fc1,   768, 3072);
    transpose_w<<<dim3(24, 96), tb, 0, stream>>>(fc2_w,    wt_fc2,   3072, 768);

    const size_t GLDS = 131072;   // 128 KiB dynamic LDS for gemm256

    u16* lnT  = slotD;
    u16* qkvT = slotA;
    ln_kernel<0><<<25088/4, 256, 0, stream>>>(x, nullptr, tn1_w, tn1_b, lnT, 25088);
    gemm256<0,false,false,false,true,false><<<dim3(9,98), 512, GLDS, stream>>>(
        lnT, wt_tqkv, nullptr, nullptr, nullptr, qkvT, 2304, 768, 768, 768, 0);

    u16* attnT = slotD;
    attn_kernel<16,1,1><<<18816/4, 256, 0, stream>>>(qkvT, attnT, 18816);

    u16* hp = slotE;
    gemm256<0,true,false,false,true,false><<<dim3(3,98), 512, GLDS, stream>>>(
        attnT, wt_tproj, t_proj_b, nullptr, nullptr, hp, 768, 768, 768, 768, 0);

    u16* xt2 = slotB;   // tfc + bias + x-residual (skip-cls map) -> bf16
    gemm256<2,true,false,false,true,false><<<dim3(3,98), 512, GLDS, stream>>>(
        hp, wt_tfc, tfc_b, x, nullptr, xt2, 768, 768, 768, 768, 0);

    u16* lnS = slotD;
    ln_kernel<1><<<25216/4, 256, 0, stream>>>(x, xt2, n1_w, n1_b, lnS, 25216);

    u16* qkvS = slotA;
    gemm256<0,false,false,false,true,true><<<dim3(9,99), 512, GLDS, stream>>>(
        lnS, wt_sqkv, nullptr, nullptr, nullptr, qkvS, 2304, 768, 768, 768, 25216);

    u16* attnS = slotD;
    attn_kernel<197,13,7><<<19968/4, 256, 0, stream>>>(qkvS, attnS, 19968);

    u16* rsb = slotE;
    gemm256<0,true,false,false,true,true><<<dim3(3,99), 512, GLDS, stream>>>(
        attnS, wt_sproj, s_proj_b, nullptr, nullptr, rsb, 768, 768, 768, 768, 25216);

    float* xnew = out;                // x_new lives in d_out
    u16* ln2 = slotD;
    combine_ln2<<<25096/4, 256, 0, stream>>>(x, xt2, rsb, n2_w, n2_b, xnew, ln2, 25096);

    // MLP split into two hidden halves (h1 fits in slotA)
    u16* h1 = slotA;
    for (int half = 0; half < 2; ++half) {
        const u16* w1h = wt_fc1 + (size_t)half * 1536 * 768;   // rows [N-half][768]
        const float* b1h = fc1_b + half * 1536;
        gemm256<0,true,true,false,true,true><<<dim3(6,99), 512, GLDS, stream>>>(
            ln2, w1h, b1h, nullptr, nullptr, h1, 1536, 768, 768, 768, 25096);
        const u16* w2h = wt_fc2 + (size_t)half * 1536;         // [768][3072] K-offset
        if (half == 0)
            gemm256<1,true,false,true,false,true><<<dim3(3,99), 512, GLDS, stream>>>(
                h1, w2h, fc2_b, out, out, nullptr, 768, 1536, 1536, 3072, 25096);
        else
            gemm256<1,false,false,true,false,true><<<dim3(3,99), 512, GLDS, stream>>>(
                h1, w2h, nullptr, out, out, nullptr, 768, 1536, 1536, 3072, 25096);
    }
}